// Round 5
// baseline (2256.804 us; speedup 1.0000x reference)
//
#include <hip/hip_runtime.h>
#include <hip/hip_bf16.h>
#include <math.h>

typedef __bf16 bf16;
typedef __bf16 bf16x4 __attribute__((ext_vector_type(4)));
typedef __bf16 bf16x8 __attribute__((ext_vector_type(8)));
typedef float f32x4 __attribute__((ext_vector_type(4)));

#define BB 64
#define NN 49
#define CENC 2048
#define SS 26
#define NSTEP 25
#define VV 10000
#define EE 512
#define HH 512
#define AAT 512
#define ALPHA_OFF (BB*NSTEP*VV)

// T16 layout for MFMA operands: M[R x K] -> sw[((rt*KC + kc)*64 + lane)*8 + j]
//   rt=r/16, kc=k/32, lane=((k%32)/8)*16 + (r%16), j=k%8, KC=K/32.
// ldb8(sw + tile*512 + lane*8) is 1KB contiguous per wave = exact MFMA fragment.

struct Wks {
  union {                                   // 27.6 MB shared region
    struct {                                // prologue-early (k_att1 input)
      bf16 feat_hi[3136*CENC];
      bf16 feat_lo[3136*CENC];
    } a;
    struct {                                // written only AFTER k_att1
      bf16  wfcn[10048*HH];                 // T16 (R=10000 pad 10048, K=512)
      float gx[NSTEP*BB*CENC];              // emb-part of gates, fp32 [1600][2048]
      float pbuf[BB*8*2048];                // per-step gate partials [b][kq][j]
    } b;
  } u;
  float att1[BB*NN*AAT];                    // fp32 row-major
  float h0[BB*HH];                          // fp32 initial h
  float c[BB*HH];                           // fp32 cell state (single buffer)
  bf16 h_hi[BB*HH];                         // T16 (R=64,K=512,KC=16)
  bf16 h_lo[BB*HH];
  bf16 ctx_hi[BB*CENC];                     // T16 (R=64,K=2048,KC=64)
  bf16 ctx_lo[BB*CENC];
  bf16 mean_hi[BB*CENC];                    // T16
  bf16 mean_lo[BB*CENC];
  bf16 xemb_hi[NSTEP*BB*EE];                // T16 (R=1600,K=512), row=s*64+b
  bf16 xemb_lo[NSTEP*BB*EE];
  bf16 hist_hi[NSTEP*BB*HH];                // T16 (R=1600,K=512), row=s*64+b
  bf16 hist_lo[NSTEP*BB*HH];
  bf16 Wih_hi[4*HH*(EE+CENC)];              // T16 (R=2048,K=2560,KC=80)
  bf16 Wih_lo[4*HH*(EE+CENC)];
  bf16 Whh_hi[4*HH*HH];                     // T16 (R=2048,K=512,KC=16)
  bf16 Whh_lo[4*HH*HH];
  bf16 Wenc_hi[AAT*CENC];                   // T16 (R=512,K=2048,KC=64)
  bf16 Wdec_hi[AAT*HH];                     // row-major (per-wave row dots)
  bf16 Winh_hi[HH*CENC];                    // T16
  bf16 Winc_hi[HH*CENC];                    // T16
};

__device__ inline bf16x8 ldb8(const bf16* p){ return *(const bf16x8*)p; }
__device__ inline f32x4 mfma16(bf16x8 a, bf16x8 b, f32x4 c){
  return __builtin_amdgcn_mfma_f32_16x16x32_bf16(a, b, c, 0, 0, 0);
}
__device__ inline float sigm(float x){ return 1.0f/(1.0f+expf(-x)); }

__device__ inline void split8(const float* p, bf16x8& hi, bf16x8& lo){
  float4 v0 = *(const float4*)p;
  float4 v1 = *(const float4*)(p+4);
  float v[8] = {v0.x,v0.y,v0.z,v0.w,v1.x,v1.y,v1.z,v1.w};
  #pragma unroll
  for (int j=0;j<8;j++){ bf16 h=(bf16)v[j]; hi[j]=h; lo[j]=(bf16)(v[j]-(float)h); }
}

// ---- fp32 -> T16 hi(+lo): COALESCED reads (thread = (row, k-chunk)), scattered 16B writes
__global__ __launch_bounds__(256) void k_cvt_sw2(const float* __restrict__ src,
    bf16* __restrict__ hi, bf16* __restrict__ lo, int R, int K){
  int i = blockIdx.x*256 + threadIdx.x;
  int k8 = K>>3;
  if (i >= R*k8) return;
  int r = i / k8, kk = (i - r*k8)*8;
  bf16x8 hv, lv;
  split8(src + (size_t)r*K + kk, hv, lv);
  int KC = K>>5, kc = kk>>5;
  int lane = ((kk>>3)&3)*16 + (r&15);
  size_t dst = (((size_t)(r>>4)*KC + kc)*64 + lane)*8;
  *(bf16x8*)(hi+dst) = hv;
  if (lo) *(bf16x8*)(lo+dst) = lv;
}

// ---- fp32 -> bf16 row-major (Wdec) ------------------------------------------------
__global__ __launch_bounds__(256) void k_cvt(const float* __restrict__ src,
    bf16* __restrict__ hi, int n4){
  int i = blockIdx.x*256 + threadIdx.x;
  if (i >= n4) return;
  float4 v = ((const float4*)src)[i];
  float a[4] = {v.x, v.y, v.z, v.w};
  bf16x4 hv;
  #pragma unroll
  for (int j=0;j<4;j++) hv[j] = (bf16)a[j];
  *(bf16x4*)(hi + i*4) = hv;
}

// ---- gather caption embeddings -> T16 (coalesced within row) ----------------------
__global__ __launch_bounds__(256) void k_emb(const int* __restrict__ caps,
    const float* __restrict__ emb, Wks* __restrict__ ws){
  int i = blockIdx.x*256 + threadIdx.x;      // 1600 * 64
  if (i >= 1600*64) return;
  int r = i>>6, kk = (i&63)*8;
  int s = r>>6, b = r&63;
  int cap = caps[b*SS + s];
  bf16x8 hv, lv;
  split8(emb + (size_t)cap*EE + kk, hv, lv);
  int kc = kk>>5, lane = ((kk>>3)&3)*16 + (r&15);
  size_t dst = (((size_t)(r>>4)*16 + kc)*64 + lane)*8;
  *(bf16x8*)(ws->xemb_hi+dst) = hv;
  *(bf16x8*)(ws->xemb_lo+dst) = lv;
}

// ---- mean over N=49 pixels -> T16 hi/lo -------------------------------------------
__global__ __launch_bounds__(256) void k_mean(const float* __restrict__ feat, Wks* __restrict__ ws){
  int idx = blockIdx.x*256 + threadIdx.x;    // 64*2048
  int b = idx >> 11, ch = idx & 2047;
  const float* p = feat + (size_t)b*NN*CENC + ch;
  float s = 0.f;
  #pragma unroll
  for (int n=0;n<NN;n++) s += p[n*CENC];
  s *= (1.0f/49.0f);
  bf16 hi = (bf16)s;
  int off = (((b>>4)*64 + (ch>>5))*64 + ((ch&31)>>3)*16 + (b&15))*8 + (ch&7);
  ws->mean_hi[off] = hi;
  ws->mean_lo[off] = (bf16)(s - (float)hi);
}

// ---- h0/c0 init (T16 operands) ----------------------------------------------------
__global__ __launch_bounds__(256) void k_init(Wks* __restrict__ ws,
    const float* __restrict__ bh, const float* __restrict__ bc){
  int wid = threadIdx.x >> 6, lane = threadIdx.x & 63;
  int w = blockIdx.x*4 + wid;                // 0..63
  int mat = w >> 5, nt = w & 31;
  int lane15 = lane & 15, quad = lane >> 4;
  const bf16* Wm = mat ? ws->Winc_hi : ws->Winh_hi;
  const float* bm = mat ? bc : bh;
  int col = nt*16 + lane15;
  f32x4 acc[4] = {};
  for (int kc=0; kc<64; kc++){
    bf16x8 bfr = ldb8(Wm + (((size_t)nt*64 + kc)*64 + lane)*8);
    #pragma unroll
    for (int t=0;t<4;t++){
      acc[t] = mfma16(ldb8(ws->mean_hi + (((size_t)t*64 + kc)*64 + lane)*8), bfr, acc[t]);
      acc[t] = mfma16(ldb8(ws->mean_lo + (((size_t)t*64 + kc)*64 + lane)*8), bfr, acc[t]);
    }
  }
  float bias = bm[col];
  #pragma unroll
  for (int t=0;t<4;t++){
    #pragma unroll
    for (int r=0;r<4;r++){
      int b = t*16 + quad*4 + r;
      float v = acc[t][r] + bias;
      if (mat == 0){
        ws->h0[b*HH + col] = v;
        bf16 hi = (bf16)v;
        int off = (((b>>4)*16 + (col>>5))*64 + ((col&31)>>3)*16 + (b&15))*8 + (col&7);
        ws->h_hi[off] = hi;
        ws->h_lo[off] = (bf16)(v - (float)hi);
      } else {
        ws->c[b*HH + col] = v;
      }
    }
  }
}

// ---- att1 = feat @ W_enc^T + b : pure T16 streaming -------------------------------
__global__ __launch_bounds__(256) void k_att1(const float* __restrict__ benc, Wks* __restrict__ ws){
  int wid = threadIdx.x>>6, lane = threadIdx.x&63;
  int w = blockIdx.x*4 + wid;                // 196 mt x 8 ng
  int mt = w >> 3, ng = w & 7;
  int lane15 = lane&15, quad = lane>>4;
  f32x4 acc[4] = {};
  for (int kc=0; kc<64; kc++){
    bf16x8 fh = ldb8(ws->u.a.feat_hi + (((size_t)mt*64 + kc)*64 + lane)*8);
    bf16x8 fl = ldb8(ws->u.a.feat_lo + (((size_t)mt*64 + kc)*64 + lane)*8);
    #pragma unroll
    for (int u2=0;u2<4;u2++){
      bf16x8 wv = ldb8(ws->Wenc_hi + (((size_t)(ng*4+u2)*64 + kc)*64 + lane)*8);
      acc[u2] = mfma16(fh, wv, acc[u2]);
      acc[u2] = mfma16(fl, wv, acc[u2]);
    }
  }
  #pragma unroll
  for (int u2=0;u2<4;u2++){
    int colb = ng*64 + u2*16 + lane15;
    float bias = benc[colb];
    #pragma unroll
    for (int r=0;r<4;r++){
      int row = mt*16 + quad*4 + r;
      ws->att1[(size_t)row*AAT + colb] = acc[u2][r] + bias;
    }
  }
}

// ---- gx = xemb @ Wih_emb^T  (all 25 steps at once, fp32 out) ----------------------
__global__ __launch_bounds__(256) void k_gx(Wks* __restrict__ ws){
  int wid = threadIdx.x>>6, lane = threadIdx.x&63;
  int mt = blockIdx.y*4 + wid;               // 64-row group of xemb, valid < 25
  int nt = blockIdx.x;                       // 64-row group of Wih (j)
  if (mt >= NSTEP) return;
  int lane15 = lane&15, quad = lane>>4;
  f32x4 acc[4][4] = {};                      // [u: j-sub][i: m-sub]
  for (int kc=0; kc<16; kc++){
    bf16x8 ah[4], al[4], wh[4], wl[4];
    #pragma unroll
    for (int i=0;i<4;i++){
      ah[i] = ldb8(ws->xemb_hi + (((size_t)(mt*4+i)*16 + kc)*64 + lane)*8);
      al[i] = ldb8(ws->xemb_lo + (((size_t)(mt*4+i)*16 + kc)*64 + lane)*8);
    }
    #pragma unroll
    for (int u2=0;u2<4;u2++){
      size_t wrt = nt*4 + u2;
      wh[u2] = ldb8(ws->Wih_hi + ((wrt*80 + kc)*64 + lane)*8);
      wl[u2] = ldb8(ws->Wih_lo + ((wrt*80 + kc)*64 + lane)*8);
    }
    #pragma unroll
    for (int u2=0;u2<4;u2++){
      #pragma unroll
      for (int i=0;i<4;i++){
        acc[u2][i] = mfma16(ah[i], wh[u2], acc[u2][i]);
        acc[u2][i] = mfma16(al[i], wh[u2], acc[u2][i]);
        acc[u2][i] = mfma16(ah[i], wl[u2], acc[u2][i]);
      }
    }
  }
  #pragma unroll
  for (int u2=0;u2<4;u2++){
    int j = nt*64 + u2*16 + lane15;
    #pragma unroll
    for (int i=0;i<4;i++){
      #pragma unroll
      for (int r=0;r<4;r++){
        int grow = mt*64 + i*16 + quad*4 + r;
        ws->u.b.gx[(size_t)grow*2048 + j] = acc[u2][i][r];
      }
    }
  }
}

// ---- per-step: LSTM epilogue(t-1) + attention(t). 64 blocks, one per batch --------
__global__ __launch_bounds__(256) void k_step(
    int t, const float* __restrict__ feat,
    const float* __restrict__ bih, const float* __restrict__ bhh,
    const float* __restrict__ bdec, const float* __restrict__ Wfull,
    const float* __restrict__ bfull,
    Wks* __restrict__ ws, float* __restrict__ out)
{
  int b = blockIdx.x;
  int tid = threadIdx.x;
  int wid = tid>>6, lane = tid&63;
  __shared__ float sh_g[2048];
  __shared__ float sh_h[512];
  __shared__ float sh_att2[512];
  __shared__ float sh_wf[512];
  __shared__ float sh_alpha[64];
  __shared__ float sh_e[64];
  if (t > 0){
    int row = (t-1)*64 + b;
    const float* gxr = ws->u.b.gx + (size_t)row*2048;
    const float* pb = ws->u.b.pbuf + (size_t)b*8*2048;
    for (int idx=tid; idx<2048; idx+=256){
      float s2 = bih[idx] + bhh[idx] + gxr[idx];
      #pragma unroll
      for (int kq=0;kq<8;kq++) s2 += pb[kq*2048 + idx];
      sh_g[idx] = s2;
    }
    __syncthreads();
    for (int jj=tid; jj<512; jj+=256){
      float iv = sh_g[jj], fv = sh_g[512+jj], gv = sh_g[1024+jj], ov = sh_g[1536+jj];
      float co = ws->c[b*HH + jj];
      float cn = sigm(fv)*co + sigm(iv)*tanhf(gv);
      float hn = sigm(ov)*tanhf(cn);
      ws->c[b*HH + jj] = cn;
      sh_h[jj] = hn;
      bf16 hv2 = (bf16)hn;
      bf16 lv2 = (bf16)(hn - (float)hv2);
      int kc = jj>>5, lanew = ((jj>>3)&3)*16 + (b&15), j8 = jj&7;
      size_t offh = (((size_t)(b>>4)*16 + kc)*64 + lanew)*8 + j8;
      ws->h_hi[offh] = hv2;
      ws->h_lo[offh] = lv2;
      size_t offhist = ((((size_t)(t-1)*4 + (b>>4))*16 + kc)*64 + lanew)*8 + j8;
      ws->hist_hi[offhist] = hv2;
      ws->hist_lo[offhist] = lv2;
    }
  } else {
    for (int jj=tid; jj<512; jj+=256) sh_h[jj] = ws->h0[b*HH + jj];
  }
  if (t >= NSTEP) return;                    // t==25: epilogue only (uniform exit)
  sh_wf[tid] = Wfull[tid]; sh_wf[tid+256] = Wfull[tid+256];
  __syncthreads();
  // att2: per-wave row dots on row-major bf16 Wdec; h broadcast from LDS
  float h8[8];
  #pragma unroll
  for (int j=0;j<8;j++) h8[j] = sh_h[lane*8 + j];
  {
    const bf16* wd = ws->Wdec_hi + (size_t)wid*128*HH + lane*8;
    #pragma unroll 2
    for (int r=0;r<128;r+=2){
      bf16x8 w0 = ldb8(wd + (size_t)r*HH);
      bf16x8 w1 = ldb8(wd + (size_t)(r+1)*HH);
      float s0=0.f, s1=0.f;
      #pragma unroll
      for (int j=0;j<8;j++){ s0 += (float)w0[j]*h8[j]; s1 += (float)w1[j]*h8[j]; }
      #pragma unroll
      for (int off=32; off; off>>=1){ s0 += __shfl_xor(s0,off,64); s1 += __shfl_xor(s1,off,64); }
      if (lane==0){
        int a0 = wid*128 + r;
        sh_att2[a0]   = s0 + bdec[a0];
        sh_att2[a0+1] = s1 + bdec[a0+1];
      }
    }
  }
  __syncthreads();
  for (int n = wid; n < NN; n += 4){
    const float* at1 = ws->att1 + (size_t)(b*NN + n)*AAT + lane*8;
    const float* a2p = sh_att2 + lane*8;
    const float* wfp = sh_wf + lane*8;
    float s = 0.f;
    #pragma unroll
    for (int j=0;j<8;j++){
      float v = at1[j] + a2p[j];
      v = fmaxf(v, 0.0f);
      s += v * wfp[j];
    }
    #pragma unroll
    for (int off=32; off; off>>=1) s += __shfl_xor(s, off, 64);
    if (lane==0) sh_e[n] = s + bfull[0];
  }
  __syncthreads();
  if (wid == 0){
    float e = (lane < NN) ? sh_e[lane] : -1e30f;
    float m = e;
    #pragma unroll
    for (int off=32; off; off>>=1) m = fmaxf(m, __shfl_xor(m, off, 64));
    float p = (lane < NN) ? expf(e - m) : 0.0f;
    float sum = p;
    #pragma unroll
    for (int off=32; off; off>>=1) sum += __shfl_xor(sum, off, 64);
    float al = p / sum;
    if (lane < NN){
      sh_alpha[lane] = al;
      out[ALPHA_OFF + (size_t)(b*NSTEP + t)*NN + lane] = al;
    }
  }
  __syncthreads();
  int ch0 = tid*8;
  float acc[8] = {};
  for (int n=0;n<NN;n++){
    float al = sh_alpha[n];
    const float* fp = feat + (size_t)(b*NN+n)*CENC + ch0;
    float4 f0 = *(const float4*)fp;
    float4 f1 = *(const float4*)(fp+4);
    float fv[8] = {f0.x,f0.y,f0.z,f0.w,f1.x,f1.y,f1.z,f1.w};
    #pragma unroll
    for (int j=0;j<8;j++) acc[j] += al*fv[j];
  }
  bf16x8 hv, lv;
  #pragma unroll
  for (int j=0;j<8;j++){
    bf16 hi = (bf16)acc[j];
    hv[j] = hi; lv[j] = (bf16)(acc[j] - (float)hi);
  }
  int off = (((b>>4)*64 + (ch0>>5))*64 + ((ch0&31)>>3)*16 + (b&15))*8;
  *(bf16x8*)(ws->ctx_hi + off) = hv;
  *(bf16x8*)(ws->ctx_lo + off) = lv;
}

// ---- per-step: gate partials. 256 blocks = 32 jt x 8 kq, weights read ONCE --------
__global__ __launch_bounds__(256) void k_step_b(Wks* __restrict__ ws)
{
  int tid = threadIdx.x;
  int g = tid>>6, lane = tid&63;             // wave = gate
  int jt = blockIdx.x & 31, kq = blockIdx.x >> 5;
  int lane15 = lane&15, quad = lane>>4;
  size_t wrt = g*32 + jt;                    // row-tile of 2048-row weights
  f32x4 acc[4] = {};                         // one per 16-batch tile
  int v0 = kq*10, v1 = v0 + 10;              // virtual kc units: 64 ctx + 16 h = 80
  int ce = v1 < 64 ? v1 : 64;
  for (int vkc=v0; vkc<ce; vkc++){           // ctx section (Wih kc = 16+vkc)
    bf16x8 wh = ldb8(ws->Wih_hi + ((wrt*80 + 16+vkc)*64 + lane)*8);
    bf16x8 wl = ldb8(ws->Wih_lo + ((wrt*80 + 16+vkc)*64 + lane)*8);
    #pragma unroll
    for (int bt=0;bt<4;bt++){
      bf16x8 ah = ldb8(ws->ctx_hi + (((size_t)bt*64 + vkc)*64 + lane)*8);
      bf16x8 al = ldb8(ws->ctx_lo + (((size_t)bt*64 + vkc)*64 + lane)*8);
      acc[bt] = mfma16(ah, wh, acc[bt]);
      acc[bt] = mfma16(al, wh, acc[bt]);
      acc[bt] = mfma16(ah, wl, acc[bt]);
    }
  }
  int hs = v0 > 64 ? v0 : 64;
  for (int vkc=hs; vkc<v1; vkc++){           // h section
    int hkc = vkc - 64;
    bf16x8 wh = ldb8(ws->Whh_hi + ((wrt*16 + hkc)*64 + lane)*8);
    bf16x8 wl = ldb8(ws->Whh_lo + ((wrt*16 + hkc)*64 + lane)*8);
    #pragma unroll
    for (int bt=0;bt<4;bt++){
      bf16x8 ah = ldb8(ws->h_hi + (((size_t)bt*16 + hkc)*64 + lane)*8);
      bf16x8 al = ldb8(ws->h_lo + (((size_t)bt*16 + hkc)*64 + lane)*8);
      acc[bt] = mfma16(ah, wh, acc[bt]);
      acc[bt] = mfma16(al, wh, acc[bt]);
      acc[bt] = mfma16(ah, wl, acc[bt]);
    }
  }
  __shared__ float st[64][68];               // +4 pad: kills bank conflicts, keeps 16B align
  #pragma unroll
  for (int bt=0;bt<4;bt++)
    #pragma unroll
    for (int r=0;r<4;r++)
      st[bt*16 + quad*4 + r][g*16 + lane15] = acc[bt][r];
  __syncthreads();
  // coalesced 64B store per thread: pbuf[b][kq][seg*512 + jt*16 .. +16]
  int b = tid>>2, seg = tid&3;
  float* dst = ws->u.b.pbuf + ((size_t)b*8 + kq)*2048 + seg*512 + jt*16;
  const float* srcl = &st[b][seg*16];
  #pragma unroll
  for (int q=0;q<4;q++) ((float4*)dst)[q] = ((const float4*)srcl)[q];
}

// ---- final pred GEMM: [1600 x 10000] = hist @ Wfcn^T (T16) ------------------------
__global__ __launch_bounds__(256) void k_pred(Wks* __restrict__ ws,
    const float* __restrict__ bfcn, float* __restrict__ out)
{
  int wid = threadIdx.x>>6, lane = threadIdx.x&63;
  int mt = blockIdx.y*4 + wid;
  int nt = blockIdx.x;
  if (mt >= NSTEP) return;
  int lane15 = lane&15, quad = lane>>4;
  int n0 = nt*64;
  f32x4 acc[4][4] = {};
  for (int kc=0; kc<16; kc++){
    bf16x8 a_hi[4], a_lo[4], bw[4];
    #pragma unroll
    for (int i=0;i<4;i++){
      a_hi[i] = ldb8(ws->hist_hi + (((size_t)(mt*4+i)*16 + kc)*64 + lane)*8);
      a_lo[i] = ldb8(ws->hist_lo + (((size_t)(mt*4+i)*16 + kc)*64 + lane)*8);
    }
    #pragma unroll
    for (int u2=0;u2<4;u2++)
      bw[u2] = ldb8(ws->u.b.wfcn + (((size_t)(nt*4+u2)*16 + kc)*64 + lane)*8);
    #pragma unroll
    for (int u2=0;u2<4;u2++){
      #pragma unroll
      for (int i=0;i<4;i++){
        acc[u2][i] = mfma16(a_hi[i], bw[u2], acc[u2][i]);
        acc[u2][i] = mfma16(a_lo[i], bw[u2], acc[u2][i]);
      }
    }
  }
  #pragma unroll
  for (int u2=0;u2<4;u2++){
    int vc = n0 + u2*16 + lane15;
    if (vc < VV){
      float bias = bfcn[vc];
      #pragma unroll
      for (int i=0;i<4;i++){
        #pragma unroll
        for (int r=0;r<4;r++){
          int row = mt*64 + i*16 + quad*4 + r;   // row = s*64 + b
          int sstep = row >> 6, bidx = row & 63;
          out[(size_t)(bidx*NSTEP + sstep)*VV + vc] = acc[u2][i][r] + bias;
        }
      }
    }
  }
}

extern "C" void kernel_launch(void* const* d_in, const int* in_sizes, int n_in,
                              void* d_out, int out_size, void* d_ws, size_t ws_size,
                              hipStream_t stream)
{
  const float* feat = (const float*)d_in[0];
  const int*   caps = (const int*)d_in[1];
  const float* emb  = (const float*)d_in[2];
  const float* Wih  = (const float*)d_in[3];
  const float* bih  = (const float*)d_in[4];
  const float* Whh  = (const float*)d_in[5];
  const float* bhh  = (const float*)d_in[6];
  const float* Wenc = (const float*)d_in[7];
  const float* benc = (const float*)d_in[8];
  const float* Wdec = (const float*)d_in[9];
  const float* bdec = (const float*)d_in[10];
  const float* Wfull= (const float*)d_in[11];
  const float* bfull= (const float*)d_in[12];
  const float* Winh = (const float*)d_in[13];
  const float* binh = (const float*)d_in[14];
  const float* Winc = (const float*)d_in[15];
  const float* binc = (const float*)d_in[16];
  const float* Wfcn = (const float*)d_in[17];
  const float* bfcn = (const float*)d_in[18];
  float* out = (float*)d_out;
  Wks* ws = (Wks*)d_ws;
  if (ws_size < sizeof(Wks)) return;

  #define SW(src, hi, lo, R, K) hipLaunchKernelGGL(k_cvt_sw2, \
      dim3(((R)*((K)/8)+255)/256), dim3(256), 0, stream, src, hi, lo, R, K)
  SW(feat, ws->u.a.feat_hi, ws->u.a.feat_lo, 3136, 2048);   // union.a live
  SW(Wih,  ws->Wih_hi,  ws->Wih_lo,  2048, 2560);
  SW(Whh,  ws->Whh_hi,  ws->Whh_lo,  2048, 512);
  SW(Wenc, ws->Wenc_hi, (bf16*)nullptr, 512, 2048);
  SW(Winh, ws->Winh_hi, (bf16*)nullptr, 512, 2048);
  SW(Winc, ws->Winc_hi, (bf16*)nullptr, 512, 2048);
  hipLaunchKernelGGL(k_cvt, dim3((AAT*HH/4+255)/256), dim3(256), 0, stream, Wdec, ws->Wdec_hi, AAT*HH/4);
  hipLaunchKernelGGL(k_emb, dim3(400), dim3(256), 0, stream, caps, emb, ws);
  hipLaunchKernelGGL(k_mean, dim3(512), dim3(256), 0, stream, feat, ws);
  hipLaunchKernelGGL(k_init, dim3(16), dim3(256), 0, stream, ws, binh, binc);
  hipLaunchKernelGGL(k_att1, dim3(392), dim3(256), 0, stream, benc, ws);
  // union.a dead after k_att1 -> union.b may now be written
  SW(Wfcn, ws->u.b.wfcn, (bf16*)nullptr, 10000, 512);
  #undef SW
  hipLaunchKernelGGL(k_gx, dim3(32, 7), dim3(256), 0, stream, ws);

  for (int t=0; t<NSTEP; t++){
    hipLaunchKernelGGL(k_step, dim3(64), dim3(256), 0, stream,
        t, feat, bih, bhh, bdec, Wfull, bfull, ws, out);
    hipLaunchKernelGGL(k_step_b, dim3(256), dim3(256), 0, stream, ws);
  }
  hipLaunchKernelGGL(k_step, dim3(64), dim3(256), 0, stream,
      NSTEP, feat, bih, bhh, bdec, Wfull, bfull, ws, out);   // final epilogue only
  hipLaunchKernelGGL(k_pred, dim3(157, 7), dim3(256), 0, stream, ws, bfcn, out);
}